// Round 4
// baseline (113.702 us; speedup 1.0000x reference)
//
#include <hip/hip_runtime.h>
#include <stdint.h>
#include <math.h>

#define NROWS 8192
#define DDIM  256
#define BM    128
#define GJ    8                         // column groups (grid.y)
#define COLS_PER_GROUP (NROWS / GJ)     // 1024

constexpr float INV_T  = 1.0f / 0.07f;  // fixed LSE max M0 = 1/T (|logit| <= ~1/T)
constexpr float LOG2E  = 1.44269504f;
constexpr float K1     = INV_T * LOG2E; // exp2 arg: fma(acc, K1, -K1)

typedef __bf16 bf16x8 __attribute__((ext_vector_type(8)));
typedef float  f32x4  __attribute__((ext_vector_type(4)));

__device__ __forceinline__ void async_copy16(const uint16_t* g, uint16_t* l) {
    __builtin_amdgcn_global_load_lds(
        (const __attribute__((address_space(1))) uint32_t*)g,
        (__attribute__((address_space(3))) uint32_t*)l, 16, 0, 0);
}

__device__ inline uint16_t f2bf(float f) {
    uint32_t u = __float_as_uint(f);
    u += 0x7fffu + ((u >> 16) & 1u);    // RNE
    return (uint16_t)(u >> 16);
}

// Kernel 1: unit-normalize rows of q and k (bf16 out) + fp32 paired cosine l_pos/T.
// One wave handles row i of BOTH q and k. 2048 blocks x 4 waves.
__global__ __launch_bounds__(256) void norm_lpos_kernel(
    const float* __restrict__ fq, const float* __restrict__ fk,
    uint16_t* __restrict__ qb, uint16_t* __restrict__ kb,
    float* __restrict__ lpT)
{
    const int wave = threadIdx.x >> 6;
    const int lane = threadIdx.x & 63;
    const int row  = blockIdx.x * 4 + wave;

    float4 vq = ((const float4*)(fq + (size_t)row * DDIM))[lane];
    float4 vk = ((const float4*)(fk + (size_t)row * DDIM))[lane];
    float sq = vq.x*vq.x + vq.y*vq.y + vq.z*vq.z + vq.w*vq.w;
    float sk = vk.x*vk.x + vk.y*vk.y + vk.z*vk.z + vk.w*vk.w;
    float dp = vq.x*vk.x + vq.y*vk.y + vq.z*vk.z + vq.w*vk.w;
    #pragma unroll
    for (int m = 1; m < 64; m <<= 1) {
        sq += __shfl_xor(sq, m, 64);
        sk += __shfl_xor(sk, m, 64);
        dp += __shfl_xor(dp, m, 64);
    }
    float rq = rsqrtf(sq), rk = rsqrtf(sk);   // norms ~16; EPS clamp unreachable

    ushort4 oq, ok;
    oq.x = f2bf(vq.x * rq); oq.y = f2bf(vq.y * rq); oq.z = f2bf(vq.z * rq); oq.w = f2bf(vq.w * rq);
    ok.x = f2bf(vk.x * rk); ok.y = f2bf(vk.y * rk); ok.z = f2bf(vk.z * rk); ok.w = f2bf(vk.w * rk);
    ((ushort4*)(qb + (size_t)row * DDIM))[lane] = oq;
    ((ushort4*)(kb + (size_t)row * DDIM))[lane] = ok;
    if (lane == 0) lpT[row] = dp * rq * rk * INV_T;   // == sim[i,i]/T, fp32-exact
}

// Kernel 2: fused GEMM + fixed-max sum-of-exp over this block's 1024-col group.
// No diag masking needed (diag term == exp(l_pos/T - M0), kept in the sum; the
// reference's masked LSE + l_pos column equals the unmasked row LSE exactly).
// Q fragments in REGISTERS (loaded once via LDS); the 64 KB LDS union then holds
// two 32 KB K buffers (BK=128, double-buffered, async). 19 barriers total.
__global__ __launch_bounds__(256, 2) void nce_main_kernel(
    const uint16_t* __restrict__ qb, const uint16_t* __restrict__ kb,
    float* __restrict__ gpl)
{
    __shared__ __align__(16) uint16_t lds[2 * 128 * 128];   // 65536 B union

    const int tid    = threadIdx.x;
    const int wave   = tid >> 6;
    const int lane   = tid & 63;
    const int quad   = lane >> 4;
    const int lanelo = lane & 15;
    const int wr     = wave >> 1;
    const int wc     = wave & 1;
    const int rowBase      = blockIdx.x * BM;
    const int colGroupBase = blockIdx.y * COLS_PER_GROUP;

    // ---- Stage Q tile (128x256) once into the whole union, source-swizzled.
    #pragma unroll
    for (int i = 0; i < 16; ++i) {
        int S   = (wave * 16 + i) * 64 + lane;
        int row = S >> 5;
        int ch  = (S & 31) ^ (row & 31);
        async_copy16(qb + (size_t)(rowBase + row) * DDIM + ch * 8,
                     lds + (size_t)(wave * 16 + i) * 512);
    }
    __syncthreads();    // Q visible

    // ---- Pull Q fragments to registers (aq[mt][kk], 128 VGPRs), then free LDS.
    bf16x8 aq[4][8];
    #pragma unroll
    for (int mt = 0; mt < 4; ++mt) {
        int rq  = wr * 64 + mt * 16 + lanelo;
        int r31 = rq & 31;
        #pragma unroll
        for (int kk = 0; kk < 8; ++kk)
            aq[mt][kk] = *(const bf16x8*)&lds[rq * 256 + (((kk << 2) + quad) ^ r31) * 8];
    }
    __syncthreads();    // all waves done reading Q; union reusable for K

    // ---- K staging constants: 8 chunks/thread per 128x128 tile, source-swizzled.
    int koff[8];
    #pragma unroll
    for (int i = 0; i < 8; ++i) {
        int S   = i * 256 + tid;
        int row = S >> 4;
        int ch  = (S & 15) ^ (row & 15);
        koff[i] = (colGroupBase + row) * DDIM + ch * 8;
    }

    // phase p (0..15): jt = p>>1, k-half h = p&1; buffer p&1.
    #pragma unroll
    for (int i = 0; i < 8; ++i)     // issue phase 0 into buf 0
        async_copy16(kb + koff[i], lds + (i * 256 + wave * 64) * 8);
    __syncthreads();    // phase 0 visible

    int bvrow[4];
    #pragma unroll
    for (int nt = 0; nt < 4; ++nt) bvrow[nt] = (wc * 64 + nt * 16 + lanelo) * 128;

    float l_run[16];
    #pragma unroll
    for (int i = 0; i < 16; ++i) l_run[i] = 0.f;

    for (int jt = 0; jt < 8; ++jt) {
        f32x4 acc[4][4];
        #pragma unroll
        for (int mt = 0; mt < 4; ++mt)
            #pragma unroll
            for (int nt = 0; nt < 4; ++nt)
                acc[mt][nt] = (f32x4){0.f, 0.f, 0.f, 0.f};

        #pragma unroll
        for (int h = 0; h < 2; ++h) {
            const int p    = jt * 2 + h;
            const int buf  = p & 1;
            const int boff = buf << 14;             // elems

            if (p < 15) {                           // prefetch phase p+1
                const int np  = p + 1;
                const int soff = ((np >> 1) << 15) + ((np & 1) << 7);
                const int doff = (buf ^ 1) << 14;
                #pragma unroll
                for (int i = 0; i < 8; ++i)
                    async_copy16(kb + koff[i] + soff,
                                 lds + doff + (i * 256 + wave * 64) * 8);
            }

            #pragma unroll
            for (int kc = 0; kc < 4; ++kc) {
                bf16x8 bv[4];
                #pragma unroll
                for (int nt = 0; nt < 4; ++nt)
                    bv[nt] = *(const bf16x8*)&lds[boff + bvrow[nt] + (((kc << 2) + quad) ^ lanelo) * 8];
                #pragma unroll
                for (int mt = 0; mt < 4; ++mt)
                    #pragma unroll
                    for (int nt = 0; nt < 4; ++nt)
                        acc[mt][nt] = __builtin_amdgcn_mfma_f32_16x16x32_bf16(
                            aq[mt][h * 4 + kc], bv[nt], acc[mt][nt], 0, 0, 0);
            }
            __syncthreads();    // publish prefetch / guard buffer reuse
        }

        // Epilogue: pure fma+exp2+add, no compares, no stores.
        #pragma unroll
        for (int mt = 0; mt < 4; ++mt)
            #pragma unroll
            for (int rg = 0; rg < 4; ++rg) {
                float s = 0.f;
                #pragma unroll
                for (int nt = 0; nt < 4; ++nt)
                    s += exp2f(fmaf(acc[mt][nt][rg], K1, -K1));
                l_run[mt * 4 + rg] += s;
            }
    }

    // Cross-lane reduce over the 16 lanelo lanes (same row, different cols).
    #pragma unroll
    for (int i = 0; i < 16; ++i) {
        float v = l_run[i];
        v += __shfl_xor(v, 1, 64);
        v += __shfl_xor(v, 2, 64);
        v += __shfl_xor(v, 4, 64);
        v += __shfl_xor(v, 8, 64);
        l_run[i] = v;
    }
    float* pl = (float*)lds;    // 256 floats scratch (all K phases drained)
    if (lanelo == 0) {
        #pragma unroll
        for (int mt = 0; mt < 4; ++mt)
            #pragma unroll
            for (int rg = 0; rg < 4; ++rg) {
                int lr = wr * 64 + mt * 16 + quad * 4 + rg;
                pl[wc * 128 + lr] = l_run[mt * 4 + rg];
            }
    }
    __syncthreads();
    if (tid < 128) {
        float L = pl[tid] + pl[128 + tid];
        gpl[(size_t)blockIdx.y * NROWS + rowBase + tid] = L;
    }
}

// Kernel 3: merge GJ partial sums; loss = M0 + log(L) - l_pos/T.
__global__ __launch_bounds__(256) void finalize_kernel(
    const float* __restrict__ gpl, const float* __restrict__ lpT,
    float* __restrict__ out)
{
    int t = blockIdx.x * 256 + threadIdx.x;
    if (t >= NROWS) return;
    float L = 0.f;
    #pragma unroll
    for (int g = 0; g < GJ; ++g) L += gpl[g * NROWS + t];
    out[t] = INV_T + __logf(L) - lpT[t];
}

extern "C" void kernel_launch(void* const* d_in, const int* in_sizes, int n_in,
                              void* d_out, int out_size, void* d_ws, size_t ws_size,
                              hipStream_t stream) {
    const float* fq = (const float*)d_in[0];
    const float* fk = (const float*)d_in[1];
    char* ws = (char*)d_ws;
    // layout: qb 4MB | kb 4MB | lpT 32KB | gpl 256KB
    uint16_t* qb  = (uint16_t*)(ws);
    uint16_t* kb  = (uint16_t*)(ws + 4194304);
    float*    lpT = (float*)(ws + 8388608);
    float*    gpl = (float*)(ws + 8421376);

    norm_lpos_kernel<<<NROWS / 4, 256, 0, stream>>>(fq, fk, qb, kb, lpT);
    dim3 grid(NROWS / BM, GJ);
    nce_main_kernel<<<grid, 256, 0, stream>>>(qb, kb, gpl);
    finalize_kernel<<<NROWS / 256, 256, 0, stream>>>(gpl, lpT, (float*)d_out);
}

// Round 5
// 113.679 us; speedup vs baseline: 1.0002x; 1.0002x over previous
//
#include <hip/hip_runtime.h>
#include <stdint.h>
#include <math.h>

#define NROWS 8192
#define DDIM  256
#define BM    128
#define GJ    8                         // column groups (grid.y)
#define COLS_PER_GROUP (NROWS / GJ)     // 1024

constexpr float INV_T  = 1.0f / 0.07f;  // fixed LSE max M0 = 1/T (|logit| <= ~1/T)
constexpr float LOG2E  = 1.44269504f;
constexpr float K1     = INV_T * LOG2E; // exp2 arg: fma(acc, K1, -K1)

typedef __bf16 bf16x8 __attribute__((ext_vector_type(8)));
typedef float  f32x4  __attribute__((ext_vector_type(4)));

__device__ __forceinline__ void async_copy16(const uint16_t* g, uint16_t* l) {
    __builtin_amdgcn_global_load_lds(
        (const __attribute__((address_space(1))) uint32_t*)g,
        (__attribute__((address_space(3))) uint32_t*)l, 16, 0, 0);
}

__device__ inline uint16_t f2bf(float f) {
    uint32_t u = __float_as_uint(f);
    u += 0x7fffu + ((u >> 16) & 1u);    // RNE
    return (uint16_t)(u >> 16);
}

// Kernel 1: unit-normalize rows of q and k (bf16 out) + fp32 paired cosine l_pos/T.
__global__ __launch_bounds__(256) void norm_lpos_kernel(
    const float* __restrict__ fq, const float* __restrict__ fk,
    uint16_t* __restrict__ qb, uint16_t* __restrict__ kb,
    float* __restrict__ lpT)
{
    const int wave = threadIdx.x >> 6;
    const int lane = threadIdx.x & 63;
    const int row  = blockIdx.x * 4 + wave;

    float4 vq = ((const float4*)(fq + (size_t)row * DDIM))[lane];
    float4 vk = ((const float4*)(fk + (size_t)row * DDIM))[lane];
    float sq = vq.x*vq.x + vq.y*vq.y + vq.z*vq.z + vq.w*vq.w;
    float sk = vk.x*vk.x + vk.y*vk.y + vk.z*vk.z + vk.w*vk.w;
    float dp = vq.x*vk.x + vq.y*vk.y + vq.z*vk.z + vq.w*vk.w;
    #pragma unroll
    for (int m = 1; m < 64; m <<= 1) {
        sq += __shfl_xor(sq, m, 64);
        sk += __shfl_xor(sk, m, 64);
        dp += __shfl_xor(dp, m, 64);
    }
    float rq = rsqrtf(sq), rk = rsqrtf(sk);   // norms ~16; EPS clamp unreachable

    ushort4 oq, ok;
    oq.x = f2bf(vq.x * rq); oq.y = f2bf(vq.y * rq); oq.z = f2bf(vq.z * rq); oq.w = f2bf(vq.w * rq);
    ok.x = f2bf(vk.x * rk); ok.y = f2bf(vk.y * rk); ok.z = f2bf(vk.z * rk); ok.w = f2bf(vk.w * rk);
    ((ushort4*)(qb + (size_t)row * DDIM))[lane] = oq;
    ((ushort4*)(kb + (size_t)row * DDIM))[lane] = ok;
    if (lane == 0) lpT[row] = dp * rq * rk * INV_T;   // == sim[i,i]/T, fp32-exact
}

// Kernel 2: fused GEMM + fixed-max sum-of-exp over this block's 1024-col group.
// Q fragments in REGISTERS (loaded once via LDS); 64 KB LDS union then holds two
// 32 KB K buffers (BK=128, double-buffered, async global_load_lds). 19 barriers.
// amdgpu_waves_per_eu(2,2): LDS caps us at 2 blocks/CU anyway; pinning max=2
// stops the allocator from squeezing to 128 VGPR and spilling aq/acc (round-4
// failure: VGPR=128 + 13.5 MB scratch writes).
__global__ __launch_bounds__(256)
__attribute__((amdgpu_waves_per_eu(2, 2)))
void nce_main_kernel(
    const uint16_t* __restrict__ qb, const uint16_t* __restrict__ kb,
    float* __restrict__ gpl)
{
    __shared__ __align__(16) uint16_t lds[2 * 128 * 128];   // 65536 B union

    const int tid    = threadIdx.x;
    const int wave   = tid >> 6;
    const int lane   = tid & 63;
    const int quad   = lane >> 4;
    const int lanelo = lane & 15;
    const int wr     = wave >> 1;
    const int wc     = wave & 1;
    const int rowBase      = blockIdx.x * BM;
    const int colGroupBase = blockIdx.y * COLS_PER_GROUP;

    // ---- Stage Q tile (128x256) once into the whole union, source-swizzled.
    #pragma unroll
    for (int i = 0; i < 16; ++i) {
        int S   = (wave * 16 + i) * 64 + lane;
        int row = S >> 5;
        int ch  = (S & 31) ^ (row & 31);
        async_copy16(qb + (size_t)(rowBase + row) * DDIM + ch * 8,
                     lds + (size_t)(wave * 16 + i) * 512);
    }
    __syncthreads();    // Q visible

    // ---- Pull Q fragments to registers (aq[mt][kk], 128 regs), then free LDS.
    bf16x8 aq[4][8];
    #pragma unroll
    for (int mt = 0; mt < 4; ++mt) {
        int rq  = wr * 64 + mt * 16 + lanelo;
        int r31 = rq & 31;
        #pragma unroll
        for (int kk = 0; kk < 8; ++kk)
            aq[mt][kk] = *(const bf16x8*)&lds[rq * 256 + (((kk << 2) + quad) ^ r31) * 8];
    }
    __syncthreads();    // all waves done reading Q; union reusable for K

    // ---- K staging constants: 8 chunks/thread per 128x128 tile, source-swizzled.
    int koff[8];
    #pragma unroll
    for (int i = 0; i < 8; ++i) {
        int S   = i * 256 + tid;
        int row = S >> 4;
        int ch  = (S & 15) ^ (row & 15);
        koff[i] = (colGroupBase + row) * DDIM + ch * 8;
    }

    // phase p (0..15): jt = p>>1, k-half h = p&1; buffer p&1.
    #pragma unroll
    for (int i = 0; i < 8; ++i)     // issue phase 0 into buf 0
        async_copy16(kb + koff[i], lds + (i * 256 + wave * 64) * 8);
    __syncthreads();    // phase 0 visible

    int bvrow[4];
    #pragma unroll
    for (int nt = 0; nt < 4; ++nt) bvrow[nt] = (wc * 64 + nt * 16 + lanelo) * 128;

    float l_run[16];
    #pragma unroll
    for (int i = 0; i < 16; ++i) l_run[i] = 0.f;

    for (int jt = 0; jt < 8; ++jt) {
        f32x4 acc[4][4];
        #pragma unroll
        for (int mt = 0; mt < 4; ++mt)
            #pragma unroll
            for (int nt = 0; nt < 4; ++nt)
                acc[mt][nt] = (f32x4){0.f, 0.f, 0.f, 0.f};

        #pragma unroll
        for (int h = 0; h < 2; ++h) {
            const int p    = jt * 2 + h;
            const int buf  = p & 1;
            const int boff = buf << 14;             // elems

            if (p < 15) {                           // prefetch phase p+1
                const int np  = p + 1;
                const int soff = ((np >> 1) << 15) + ((np & 1) << 7);
                const int doff = (buf ^ 1) << 14;
                #pragma unroll
                for (int i = 0; i < 8; ++i)
                    async_copy16(kb + koff[i] + soff,
                                 lds + doff + (i * 256 + wave * 64) * 8);
            }

            #pragma unroll
            for (int kc = 0; kc < 4; ++kc) {
                bf16x8 bv[4];
                #pragma unroll
                for (int nt = 0; nt < 4; ++nt)
                    bv[nt] = *(const bf16x8*)&lds[boff + bvrow[nt] + (((kc << 2) + quad) ^ lanelo) * 8];
                #pragma unroll
                for (int mt = 0; mt < 4; ++mt)
                    #pragma unroll
                    for (int nt = 0; nt < 4; ++nt)
                        acc[mt][nt] = __builtin_amdgcn_mfma_f32_16x16x32_bf16(
                            aq[mt][h * 4 + kc], bv[nt], acc[mt][nt], 0, 0, 0);
            }
            __syncthreads();    // publish prefetch / guard buffer reuse
        }

        // Epilogue: pure fma+exp2+add, no compares, no stores.
        #pragma unroll
        for (int mt = 0; mt < 4; ++mt)
            #pragma unroll
            for (int rg = 0; rg < 4; ++rg) {
                float s = 0.f;
                #pragma unroll
                for (int nt = 0; nt < 4; ++nt)
                    s += exp2f(fmaf(acc[mt][nt][rg], K1, -K1));
                l_run[mt * 4 + rg] += s;
            }
    }

    // Cross-lane reduce over the 16 lanelo lanes (same row, different cols).
    #pragma unroll
    for (int i = 0; i < 16; ++i) {
        float v = l_run[i];
        v += __shfl_xor(v, 1, 64);
        v += __shfl_xor(v, 2, 64);
        v += __shfl_xor(v, 4, 64);
        v += __shfl_xor(v, 8, 64);
        l_run[i] = v;
    }
    float* pl = (float*)lds;    // 256 floats scratch (all K phases drained)
    if (lanelo == 0) {
        #pragma unroll
        for (int mt = 0; mt < 4; ++mt)
            #pragma unroll
            for (int rg = 0; rg < 4; ++rg) {
                int lr = wr * 64 + mt * 16 + quad * 4 + rg;
                pl[wc * 128 + lr] = l_run[mt * 4 + rg];
            }
    }
    __syncthreads();
    if (tid < 128) {
        float L = pl[tid] + pl[128 + tid];
        gpl[(size_t)blockIdx.y * NROWS + rowBase + tid] = L;
    }
}

// Kernel 3: merge GJ partial sums; loss = M0 + log(L) - l_pos/T.
__global__ __launch_bounds__(256) void finalize_kernel(
    const float* __restrict__ gpl, const float* __restrict__ lpT,
    float* __restrict__ out)
{
    int t = blockIdx.x * 256 + threadIdx.x;
    if (t >= NROWS) return;
    float L = 0.f;
    #pragma unroll
    for (int g = 0; g < GJ; ++g) L += gpl[g * NROWS + t];
    out[t] = INV_T + __logf(L) - lpT[t];
}

extern "C" void kernel_launch(void* const* d_in, const int* in_sizes, int n_in,
                              void* d_out, int out_size, void* d_ws, size_t ws_size,
                              hipStream_t stream) {
    const float* fq = (const float*)d_in[0];
    const float* fk = (const float*)d_in[1];
    char* ws = (char*)d_ws;
    // layout: qb 4MB | kb 4MB | lpT 32KB | gpl 256KB
    uint16_t* qb  = (uint16_t*)(ws);
    uint16_t* kb  = (uint16_t*)(ws + 4194304);
    float*    lpT = (float*)(ws + 8388608);
    float*    gpl = (float*)(ws + 8421376);

    norm_lpos_kernel<<<NROWS / 4, 256, 0, stream>>>(fq, fk, qb, kb, lpT);
    dim3 grid(NROWS / BM, GJ);
    nce_main_kernel<<<grid, 256, 0, stream>>>(qb, kb, gpl);
    finalize_kernel<<<NROWS / 256, 256, 0, stream>>>(gpl, lpT, (float*)d_out);
}